// Round 7
// baseline (410.751 us; speedup 1.0000x reference)
//
#include <hip/hip_runtime.h>

// ConvLSTM2D x2 encoder — fp16 MFMA implicit-GEMM, round 15.
// R14: 383us, absmax 0.0156 (bit-exact target). Model: conv LDS floor
// ~16us/CU + stage/epilogue ~8 vs ~35 measured -> residual is per-chunk
// barrier convergence/wave skew, not bytes. Geometry levers exhausted
// (M=128 -> R13 spill cliff; 3 blk/CU -> LDS floor; smaller M -> 2x B-reads,
// R10 trap). This round, two riskless levers, math byte-identical:
// (1) T5 s_setprio(1) around the 16-MFMA cluster (phase-role diversity
//     exists: 2 interleaved blocks/CU, stage-vs-MFMA wave roles).
// (2) Bijective XCD swizzle: z=(P&7)+8*(P>>8), y=(P>>5)&7, x=(P>>3)&3 —
//     all blocks of batch b (L0+L1 roles) land on XCD b&7: halo + shared
//     h0-tile reads become same-L2 hits (heavy 512 and light 256 grids ok).

typedef _Float16 f16x8 __attribute__((ext_vector_type(8)));
typedef float f32x4 __attribute__((ext_vector_type(4)));

#define BHWF (8 * 64 * 64 * 64)
#define TSTRIDE 72                // LDS cell stride (fp16 units)
#define NCELL 180                 // 10 rows x 18 cols halo tile (16x8 px)

__device__ __forceinline__ float hsig(float x) {
    return fminf(fmaxf(fmaf(0.2f, x, 0.5f), 0.0f), 1.0f);
}

__device__ __forceinline__ float ftanh(float x) {
    float e = __expf(2.0f * x);
    return fmaf(-2.0f, __builtin_amdgcn_rcpf(e + 1.0f), 1.0f);
}

__device__ __forceinline__ ushort f2h(float f) {
    _Float16 h = (_Float16)f;     // v_cvt_f16_f32, RNE
    return __builtin_bit_cast(ushort, h);
}

// y=0..2: swizzle fp32 W[k=576][n=256] -> fp16 fragment-linear frames
//   (frame = tap*2+kc, 8192 ushorts each). y=3: Wx0 K=32-padded frames.
__global__ void prep_w(const float* __restrict__ s0, const float* __restrict__ s1,
                       const float* __restrict__ s2, const float* __restrict__ wx0,
                       ushort* __restrict__ d0, ushort* __restrict__ d1,
                       ushort* __restrict__ d2, ushort* __restrict__ dx0) {
    int o = blockIdx.x * 256 + threadIdx.x;
    if (blockIdx.y == 3) {
        if (o < 8192) {
            int e    = o & 7;
            int lane = (o >> 3) & 63;
            int g    = (o >> 9) & 3;
            int fq   = (o >> 11) & 3;
            int k = (lane >> 4) * 8 + e;
            int n = g * 64 + fq * 16 + (lane & 15);
            dx0[o] = (k < 9) ? f2h(wx0[k * 256 + n]) : (ushort)0;
        }
        return;
    }
    const float* s[3] = { s0, s1, s2 };
    ushort* d[3] = { d0, d1, d2 };
    int e    = o & 7;
    int lane = (o >> 3) & 63;
    int g    = (o >> 9) & 3;
    int fq   = (o >> 11) & 3;
    int kc   = (o >> 13) & 1;
    int tap  = o >> 14;
    int n = g * 64 + fq * 16 + (lane & 15);
    int k = tap * 64 + kc * 32 + (lane >> 4) * 8 + e;
    d[blockIdx.y][o] = f2h(s[blockIdx.y][k * 256 + n]);
}

// Stage 10x18 halo tile of fp16 [4096][64] image into LDS [cell][TSTRIDE].
__device__ __forceinline__ void stage(const ushort* __restrict__ src,
                                      ushort* __restrict__ tile,
                                      int y0, int x0, int tid) {
    for (int v = tid; v < NCELL * 8; v += 512) {
        int cell = v >> 3, j = v & 7;
        int r = cell / 18, cc = cell - r * 18;
        int y = y0 - 1 + r, xx = x0 - 1 + cc;
        uint4 dv = make_uint4(0u, 0u, 0u, 0u);
        if ((unsigned)y < 64u && (unsigned)xx < 64u)
            dv = ((const uint4*)src)[(size_t)((y << 6) + xx) * 8 + j];
        *(uint4*)&tile[cell * TSTRIDE + j * 8] = dv;
    }
}

__device__ __forceinline__ int frame_of(int c) {
    int kc = c / 9, r = c % 9, dxx = r / 3, dyy = r % 3;
    return (dyy * 3 + dxx) * 2 + kc;
}

// One frame = 16KB staged block-wide by 512 threads: 2 DMA ops x 16B/thread.
__device__ __forceinline__ void dma_frame(const ushort* __restrict__ src,
                                          ushort* __restrict__ dst, int tid) {
    __builtin_amdgcn_global_load_lds(
        (const __attribute__((address_space(1))) unsigned int*)(src + tid * 8),
        (__attribute__((address_space(3))) unsigned int*)(dst + tid * 8),
        16, 0, 0);
    __builtin_amdgcn_global_load_lds(
        (const __attribute__((address_space(1))) unsigned int*)(src + 4096 + tid * 8),
        (__attribute__((address_space(3))) unsigned int*)(dst + 4096 + tid * 8),
        16, 0, 0);
}

// 3x3x64 conv, block tile 16x8 px, 8 waves (mw 2-way M, fq 4-way N).
// B: LDS 3-deep ring, 1 frame/chunk staged cooperatively (2 DMA ops),
// counted vmcnt(2), raw s_barrier. Chunk c: kc=c/9, dx=(c%9)/3, dy=c%3.
// A: rows mw*4+{1..4} cached in C1..C4 per (kc,dx) group; rows 0/5 read
// fresh at dy==0/2. MFMA cluster wrapped in s_setprio(1/0) (T5).
__device__ __forceinline__ void conv_stream(const ushort* __restrict__ tile,
                                            const ushort* __restrict__ WS,
                                            ushort* __restrict__ bbuf,
                                            f32x4 (&acc)[4][4],
                                            int fq, int mw, int lane, int tid) {
    const int colA = lane & 15;
    const int quad = (lane >> 4) & 3;
    __syncthreads();                       // prior readers of bbuf/xa done
    dma_frame(WS + (size_t)frame_of(0) * 8192, bbuf, tid);
    dma_frame(WS + (size_t)frame_of(1) * 8192, bbuf + 8192, tid);
    __asm__ volatile("s_waitcnt vmcnt(2)\ns_barrier" ::: "memory");
    f16x8 C1, C2, C3, C4;
#pragma unroll
    for (int c = 0; c < 18; ++c) {
        if (c <= 15)
            dma_frame(WS + (size_t)frame_of(c + 2) * 8192,
                      bbuf + ((c + 2) % 3) * 8192, tid);
        const int kc = c / 9, dx = (c % 9) / 3, dy = c % 3;
        const ushort* arow = &tile[((mw * 4) * 18 + colA + dx) * TSTRIDE
                                   + kc * 32 + quad * 8];
        f16x8 m0, m1, m2, m3;
        if (dy == 0) {
            m0 = *(const f16x8*)&arow[0 * 18 * TSTRIDE];
            C1 = *(const f16x8*)&arow[1 * 18 * TSTRIDE];
            C2 = *(const f16x8*)&arow[2 * 18 * TSTRIDE];
            C3 = *(const f16x8*)&arow[3 * 18 * TSTRIDE];
            m1 = C1; m2 = C2; m3 = C3;
        } else if (dy == 1) {
            C4 = *(const f16x8*)&arow[4 * 18 * TSTRIDE];
            m0 = C1; m1 = C2; m2 = C3; m3 = C4;
        } else {
            f16x8 a5 = *(const f16x8*)&arow[5 * 18 * TSTRIDE];
            m0 = C2; m1 = C3; m2 = C4; m3 = a5;
        }
        const ushort* bp = bbuf + (c % 3) * 8192 + fq * 2048 + lane * 8;
        f16x8 B0 = *(const f16x8*)&bp[0];
        f16x8 B1 = *(const f16x8*)&bp[512];
        f16x8 B2 = *(const f16x8*)&bp[1024];
        f16x8 B3 = *(const f16x8*)&bp[1536];
        __builtin_amdgcn_s_setprio(1);
        acc[0][0] = __builtin_amdgcn_mfma_f32_16x16x32_f16(m0, B0, acc[0][0], 0, 0, 0);
        acc[0][1] = __builtin_amdgcn_mfma_f32_16x16x32_f16(m0, B1, acc[0][1], 0, 0, 0);
        acc[0][2] = __builtin_amdgcn_mfma_f32_16x16x32_f16(m0, B2, acc[0][2], 0, 0, 0);
        acc[0][3] = __builtin_amdgcn_mfma_f32_16x16x32_f16(m0, B3, acc[0][3], 0, 0, 0);
        acc[1][0] = __builtin_amdgcn_mfma_f32_16x16x32_f16(m1, B0, acc[1][0], 0, 0, 0);
        acc[1][1] = __builtin_amdgcn_mfma_f32_16x16x32_f16(m1, B1, acc[1][1], 0, 0, 0);
        acc[1][2] = __builtin_amdgcn_mfma_f32_16x16x32_f16(m1, B2, acc[1][2], 0, 0, 0);
        acc[1][3] = __builtin_amdgcn_mfma_f32_16x16x32_f16(m1, B3, acc[1][3], 0, 0, 0);
        acc[2][0] = __builtin_amdgcn_mfma_f32_16x16x32_f16(m2, B0, acc[2][0], 0, 0, 0);
        acc[2][1] = __builtin_amdgcn_mfma_f32_16x16x32_f16(m2, B1, acc[2][1], 0, 0, 0);
        acc[2][2] = __builtin_amdgcn_mfma_f32_16x16x32_f16(m2, B2, acc[2][2], 0, 0, 0);
        acc[2][3] = __builtin_amdgcn_mfma_f32_16x16x32_f16(m2, B3, acc[2][3], 0, 0, 0);
        acc[3][0] = __builtin_amdgcn_mfma_f32_16x16x32_f16(m3, B0, acc[3][0], 0, 0, 0);
        acc[3][1] = __builtin_amdgcn_mfma_f32_16x16x32_f16(m3, B1, acc[3][1], 0, 0, 0);
        acc[3][2] = __builtin_amdgcn_mfma_f32_16x16x32_f16(m3, B2, acc[3][2], 0, 0, 0);
        acc[3][3] = __builtin_amdgcn_mfma_f32_16x16x32_f16(m3, B3, acc[3][3], 0, 0, 0);
        __builtin_amdgcn_s_setprio(0);
        if (c <= 15)
            __asm__ volatile("s_waitcnt vmcnt(2)\ns_barrier" ::: "memory");
        else if (c == 16)
            __asm__ volatile("s_waitcnt vmcnt(0)\ns_barrier" ::: "memory");
        else
            __asm__ volatile("s_barrier" ::: "memory");
    }
}

// Merged step: logical z<8 -> L0 at time t, z>=8 -> L1 at time t-1.
__global__ __launch_bounds__(512, 4) void step_merged(
    int l0_active, int l1_active, int last0, int last1,
    const float* __restrict__ x, const ushort* __restrict__ Wx0F,
    const ushort* __restrict__ Wh0S, const float* __restrict__ b0,
    const ushort* __restrict__ h0_prev, float* __restrict__ c0,
    ushort* __restrict__ h0_out, float* __restrict__ oh0, float* __restrict__ oc0,
    const ushort* __restrict__ xin, const ushort* __restrict__ Wx1S,
    const ushort* __restrict__ Wh1S, const float* __restrict__ b1,
    const ushort* __restrict__ h1_prev, float* __restrict__ c1,
    ushort* __restrict__ h1_out, float* __restrict__ oh1, float* __restrict__ oc1)
{
    __shared__ __align__(16) ushort tile[NCELL * TSTRIDE];   // 25,920 B
    __shared__ __align__(16) ushort bbuf[3 * 8192];          // 49,152 B ring
    ushort* xa = bbuf;                                       // alias: L0 im2col

    // Bijective XCD swizzle: P = z*32+y*4+x (x-fastest dispatch order);
    // logical z=(P&7)+8*(P>>8), y=(P>>5)&7, x=(P>>3)&3. All blocks of
    // batch b (both roles) land on XCD b&7; valid for 512 & 256 grids.
    const int P  = (blockIdx.z * gridDim.y + blockIdx.y) * gridDim.x + blockIdx.x;
    const int xb = (P >> 3) & 3;
    const int yb = (P >> 5) & 7;
    const int zb = (P & 7) + ((P >> 8) << 3);

    bool isL1; int b;
    if (l0_active && l1_active) { isL1 = (zb >= 8); b = zb & 7; }
    else                        { isL1 = (l1_active != 0); b = zb; }

    const int tid = threadIdx.x;
    const int lane = tid & 63;
    const int w = tid >> 6;             // wave id 0..7
    const int fq = w & 3;               // f quad (N split)
    const int mw = w >> 2;              // 4-row band (M split), 0..1
    const int colA = lane & 15;
    const int quad = (lane >> 4) & 3;
    const int x0 = xb * 16, y0 = yb * 8;
    const int blk = yb * 4 + xb;        // 0..31 px-tile id
    const int f = fq * 16 + colA;

    const ushort* h_prev = isL1 ? h1_prev : h0_prev;
    const float*  bias   = isL1 ? b1 : b0;
    float*        cbuf   = isL1 ? c1 : c0;
    ushort*       hout   = isL1 ? h1_out : h0_out;
    float* hf = isL1 ? (last1 ? oh1 : nullptr) : (last0 ? oh0 : nullptr);
    float* cf = isL1 ? (last1 ? oc1 : nullptr) : (last0 ? oc0 : nullptr);

    // ---- stage first A source ----
    if (!isL1) {
        const float* xs = x + (size_t)b * 40960;
        for (int idx = tid; idx < 4096; idx += 512) {
            int e = idx & 7, li = (idx >> 3) & 63, r = idx >> 9;   // r 0..7
            int ci = li & 15, qi = li >> 4;
            int k = qi * 8 + e;
            ushort val = 0;
            if (k < 9) {
                int dy = (k * 86) >> 8;
                int dx = k - dy * 3;
                int y = y0 + r + dy - 1, xx = x0 + ci + dx - 1;
                if ((unsigned)y < 64u && (unsigned)xx < 64u)
                    val = f2h(xs[(y << 6) + xx]);
            }
            xa[idx] = val;
        }
        if (h_prev) stage(h_prev + (size_t)b * 4096 * 64, tile, y0, x0, tid);
    } else {
        stage(xin + (size_t)b * 4096 * 64, tile, y0, x0, tid);
    }
    __syncthreads();

    // ---- init accumulators with bias ----
    f32x4 acc[4][4];
#pragma unroll
    for (int g = 0; g < 4; ++g) {
        float bv = bias[g * 64 + f];
#pragma unroll
        for (int mt = 0; mt < 4; ++mt) {
            acc[mt][g][0] = bv; acc[mt][g][1] = bv;
            acc[mt][g][2] = bv; acc[mt][g][3] = bv;
        }
    }

    if (!isL1) {
        // x-conv via MFMA (K=32-padded Wx0 frames); xa lives in bbuf[0]
        f16x8 xb4[4];
#pragma unroll
        for (int g = 0; g < 4; ++g)
            xb4[g] = *(const f16x8*)&Wx0F[((fq * 4 + g) * 64 + lane) * 8];
#pragma unroll
        for (int mt = 0; mt < 4; ++mt) {
            f16x8 xaf = *(const f16x8*)&xa[(mw * 4 + mt) * 512 + lane * 8];
#pragma unroll
            for (int g = 0; g < 4; ++g)
                acc[mt][g] = __builtin_amdgcn_mfma_f32_16x16x32_f16(
                    xaf, xb4[g], acc[mt][g], 0, 0, 0);
        }
        if (h_prev) conv_stream(tile, Wh0S, bbuf, acc, fq, mw, lane, tid);
    } else {
        conv_stream(tile, Wx1S, bbuf, acc, fq, mw, lane, tid);
        if (h_prev) {
            __syncthreads();
            stage(h_prev + (size_t)b * 4096 * 64, tile, y0, x0, tid);
            __syncthreads();
            conv_stream(tile, Wh1S, bbuf, acc, fq, mw, lane, tid);
        }
    }

    // ---- LSTM pointwise epilogue ----
    // cbuf private layout (lane-linear): ((((b*32+blk)*8+w)*4+mt)*4+reg)*64+lane
#pragma unroll
    for (int mt = 0; mt < 4; ++mt) {
        const int y = y0 + mw * 4 + mt;
#pragma unroll
        for (int reg = 0; reg < 4; ++reg) {
            const int xx = x0 + quad * 4 + reg;
            const size_t cidx = (((((size_t)b * 32 + blk) * 8 + w) * 4 + mt) * 4
                                 + reg) * 64 + lane;
            const size_t pidx = ((size_t)b * 4096 + (y << 6) + xx) * 64 + f;
            float cp = h_prev ? cbuf[cidx] : 0.f;
            float iv = hsig(acc[mt][0][reg]);
            float fv = hsig(acc[mt][1][reg]);
            float gv = ftanh(acc[mt][2][reg]);
            float ov = hsig(acc[mt][3][reg]);
            float cn = fmaf(fv, cp, iv * gv);
            float hn = ov * ftanh(cn);
            cbuf[cidx] = cn;
            hout[pidx] = f2h(hn);
            if (hf) { hf[pidx] = hn; cf[pidx] = cn; }
        }
    }
}

extern "C" void kernel_launch(void* const* d_in, const int* in_sizes, int n_in,
                              void* d_out, int out_size, void* d_ws, size_t ws_size,
                              hipStream_t stream) {
    const float* x   = (const float*)d_in[0];
    const float* Wx0 = (const float*)d_in[1];
    const float* Wh0 = (const float*)d_in[2];
    const float* b0  = (const float*)d_in[3];
    const float* Wx1 = (const float*)d_in[4];
    const float* Wh1 = (const float*)d_in[5];
    const float* b1  = (const float*)d_in[6];
    float* out = (float*)d_out;
    char* ws = (char*)d_ws;

    ushort* h0buf[2] = { (ushort*)ws, (ushort*)(ws + 4u * 1024 * 1024) };
    ushort* h1buf[2] = { (ushort*)(ws + 8u * 1024 * 1024), (ushort*)(ws + 12u * 1024 * 1024) };
    float* c0 = (float*)(ws + 16u * 1024 * 1024);
    float* c1 = (float*)(ws + 24u * 1024 * 1024);
    ushort* Wh0S = (ushort*)(ws + 32u * 1024 * 1024);
    ushort* Wx1S = Wh0S + 147456;
    ushort* Wh1S = Wx1S + 147456;
    ushort* Wx0F = Wh1S + 147456;

    prep_w<<<dim3(576, 4), 256, 0, stream>>>(Wh0, Wx1, Wh1, Wx0,
                                             Wh0S, Wx1S, Wh1S, Wx0F);

    for (int t = 0; t <= 10; ++t) {
        const int has0 = (t < 10), has1 = (t >= 1);
        const int s = t - 1;
        const int tx = has0 ? t : 9;
        dim3 grid(4, 8, (has0 && has1) ? 16 : 8);
        step_merged<<<grid, 512, 0, stream>>>(
            has0, has1, (t == 9), (s == 9),
            x + (size_t)tx * 4096, Wx0F,
            (t >= 1) ? Wh0S : nullptr, b0,
            (t >= 1 && has0) ? h0buf[(t - 1) & 1] : nullptr, c0,
            h0buf[t & 1], out, out + BHWF,
            has1 ? h0buf[s & 1] : nullptr, Wx1S,
            Wh1S, b1,
            (s >= 1) ? h1buf[(s - 1) & 1] : nullptr, c1,
            h1buf[s & 1], out + 2 * (size_t)BHWF, out + 3 * (size_t)BHWF);
    }
}

// Round 8
// 403.960 us; speedup vs baseline: 1.0168x; 1.0168x over previous
//
#include <hip/hip_runtime.h>

// ConvLSTM2D x2 encoder — fp16 MFMA implicit-GEMM, round 16.
// R15 post-mortem: setprio in a barrier-lockstep chunk loop = m190's known
// regression (-28us); swizzle ~neutral. Drop setprio, keep swizzle.
// New lever (0 reg pressure, vmcnt in-order-safe): pre-issue frames 0,1 of
// each conv at the TOP of the phase (before tile stage / restage). DMA flies
// concurrently with stage global-loads; the phase-ending __syncthreads
// drains vmcnt(0) anyway, so the conv starts with frames resident instead
// of eating 2x16KB fetch + L2 latency serially. Ring re-indexed slot=(c+1)%3
// so slot0 (xa alias) is only overwritten by f2 after conv entry.
// Roofline note: 383us ~= 757 TF eff ~= 38% dense f16 peak (m97-class).

typedef _Float16 f16x8 __attribute__((ext_vector_type(8)));
typedef float f32x4 __attribute__((ext_vector_type(4)));

#define BHWF (8 * 64 * 64 * 64)
#define TSTRIDE 72                // LDS cell stride (fp16 units)
#define NCELL 180                 // 10 rows x 18 cols halo tile (16x8 px)

__device__ __forceinline__ float hsig(float x) {
    return fminf(fmaxf(fmaf(0.2f, x, 0.5f), 0.0f), 1.0f);
}

__device__ __forceinline__ float ftanh(float x) {
    float e = __expf(2.0f * x);
    return fmaf(-2.0f, __builtin_amdgcn_rcpf(e + 1.0f), 1.0f);
}

__device__ __forceinline__ ushort f2h(float f) {
    _Float16 h = (_Float16)f;     // v_cvt_f16_f32, RNE
    return __builtin_bit_cast(ushort, h);
}

// y=0..2: swizzle fp32 W[k=576][n=256] -> fp16 fragment-linear frames
//   (frame = tap*2+kc, 8192 ushorts each). y=3: Wx0 K=32-padded frames.
__global__ void prep_w(const float* __restrict__ s0, const float* __restrict__ s1,
                       const float* __restrict__ s2, const float* __restrict__ wx0,
                       ushort* __restrict__ d0, ushort* __restrict__ d1,
                       ushort* __restrict__ d2, ushort* __restrict__ dx0) {
    int o = blockIdx.x * 256 + threadIdx.x;
    if (blockIdx.y == 3) {
        if (o < 8192) {
            int e    = o & 7;
            int lane = (o >> 3) & 63;
            int g    = (o >> 9) & 3;
            int fq   = (o >> 11) & 3;
            int k = (lane >> 4) * 8 + e;
            int n = g * 64 + fq * 16 + (lane & 15);
            dx0[o] = (k < 9) ? f2h(wx0[k * 256 + n]) : (ushort)0;
        }
        return;
    }
    const float* s[3] = { s0, s1, s2 };
    ushort* d[3] = { d0, d1, d2 };
    int e    = o & 7;
    int lane = (o >> 3) & 63;
    int g    = (o >> 9) & 3;
    int fq   = (o >> 11) & 3;
    int kc   = (o >> 13) & 1;
    int tap  = o >> 14;
    int n = g * 64 + fq * 16 + (lane & 15);
    int k = tap * 64 + kc * 32 + (lane >> 4) * 8 + e;
    d[blockIdx.y][o] = f2h(s[blockIdx.y][k * 256 + n]);
}

// Stage 10x18 halo tile of fp16 [4096][64] image into LDS [cell][TSTRIDE].
__device__ __forceinline__ void stage(const ushort* __restrict__ src,
                                      ushort* __restrict__ tile,
                                      int y0, int x0, int tid) {
    for (int v = tid; v < NCELL * 8; v += 512) {
        int cell = v >> 3, j = v & 7;
        int r = cell / 18, cc = cell - r * 18;
        int y = y0 - 1 + r, xx = x0 - 1 + cc;
        uint4 dv = make_uint4(0u, 0u, 0u, 0u);
        if ((unsigned)y < 64u && (unsigned)xx < 64u)
            dv = ((const uint4*)src)[(size_t)((y << 6) + xx) * 8 + j];
        *(uint4*)&tile[cell * TSTRIDE + j * 8] = dv;
    }
}

__device__ __forceinline__ int frame_of(int c) {
    int kc = c / 9, r = c % 9, dxx = r / 3, dyy = r % 3;
    return (dyy * 3 + dxx) * 2 + kc;
}

// One frame = 16KB staged block-wide by 512 threads: 2 DMA ops x 16B/thread.
__device__ __forceinline__ void dma_frame(const ushort* __restrict__ src,
                                          ushort* __restrict__ dst, int tid) {
    __builtin_amdgcn_global_load_lds(
        (const __attribute__((address_space(1))) unsigned int*)(src + tid * 8),
        (__attribute__((address_space(3))) unsigned int*)(dst + tid * 8),
        16, 0, 0);
    __builtin_amdgcn_global_load_lds(
        (const __attribute__((address_space(1))) unsigned int*)(src + 4096 + tid * 8),
        (__attribute__((address_space(3))) unsigned int*)(dst + 4096 + tid * 8),
        16, 0, 0);
}

// Pre-issue frames 0,1 into ring slots 1,2 (slot = (c+1)%3). Safe anywhere
// after the previous conv's final barrier; overlaps with stage global-loads.
__device__ __forceinline__ void preissue(const ushort* __restrict__ WS,
                                         ushort* __restrict__ bbuf, int tid) {
    dma_frame(WS + (size_t)frame_of(0) * 8192, bbuf + 8192, tid);
    dma_frame(WS + (size_t)frame_of(1) * 8192, bbuf + 16384, tid);
}

// 3x3x64 conv, block tile 16x8 px, 8 waves (mw 2-way M, fq 4-way N).
// Caller must preissue() frames 0,1 and __syncthreads() (which drains
// vmcnt(0)) before calling. Frame c lives in slot (c+1)%3; chunk c issues
// f(c+2) into slot c%3 (fenced by chunk c-1's barrier). Counted vmcnt(2),
// raw s_barrier. A-rows mw*4+{1..4} cached C1..C4 per (kc,dx) group.
__device__ __forceinline__ void conv_stream(const ushort* __restrict__ tile,
                                            const ushort* __restrict__ WS,
                                            ushort* __restrict__ bbuf,
                                            f32x4 (&acc)[4][4],
                                            int fq, int mw, int lane, int tid) {
    const int colA = lane & 15;
    const int quad = (lane >> 4) & 3;
    f16x8 C1, C2, C3, C4;
#pragma unroll
    for (int c = 0; c < 18; ++c) {
        if (c <= 15)
            dma_frame(WS + (size_t)frame_of(c + 2) * 8192,
                      bbuf + (c % 3) * 8192, tid);
        const int kc = c / 9, dx = (c % 9) / 3, dy = c % 3;
        const ushort* arow = &tile[((mw * 4) * 18 + colA + dx) * TSTRIDE
                                   + kc * 32 + quad * 8];
        f16x8 m0, m1, m2, m3;
        if (dy == 0) {
            m0 = *(const f16x8*)&arow[0 * 18 * TSTRIDE];
            C1 = *(const f16x8*)&arow[1 * 18 * TSTRIDE];
            C2 = *(const f16x8*)&arow[2 * 18 * TSTRIDE];
            C3 = *(const f16x8*)&arow[3 * 18 * TSTRIDE];
            m1 = C1; m2 = C2; m3 = C3;
        } else if (dy == 1) {
            C4 = *(const f16x8*)&arow[4 * 18 * TSTRIDE];
            m0 = C1; m1 = C2; m2 = C3; m3 = C4;
        } else {
            f16x8 a5 = *(const f16x8*)&arow[5 * 18 * TSTRIDE];
            m0 = C2; m1 = C3; m2 = C4; m3 = a5;
        }
        const ushort* bp = bbuf + ((c + 1) % 3) * 8192 + fq * 2048 + lane * 8;
        f16x8 B0 = *(const f16x8*)&bp[0];
        f16x8 B1 = *(const f16x8*)&bp[512];
        f16x8 B2 = *(const f16x8*)&bp[1024];
        f16x8 B3 = *(const f16x8*)&bp[1536];
        acc[0][0] = __builtin_amdgcn_mfma_f32_16x16x32_f16(m0, B0, acc[0][0], 0, 0, 0);
        acc[0][1] = __builtin_amdgcn_mfma_f32_16x16x32_f16(m0, B1, acc[0][1], 0, 0, 0);
        acc[0][2] = __builtin_amdgcn_mfma_f32_16x16x32_f16(m0, B2, acc[0][2], 0, 0, 0);
        acc[0][3] = __builtin_amdgcn_mfma_f32_16x16x32_f16(m0, B3, acc[0][3], 0, 0, 0);
        acc[1][0] = __builtin_amdgcn_mfma_f32_16x16x32_f16(m1, B0, acc[1][0], 0, 0, 0);
        acc[1][1] = __builtin_amdgcn_mfma_f32_16x16x32_f16(m1, B1, acc[1][1], 0, 0, 0);
        acc[1][2] = __builtin_amdgcn_mfma_f32_16x16x32_f16(m1, B2, acc[1][2], 0, 0, 0);
        acc[1][3] = __builtin_amdgcn_mfma_f32_16x16x32_f16(m1, B3, acc[1][3], 0, 0, 0);
        acc[2][0] = __builtin_amdgcn_mfma_f32_16x16x32_f16(m2, B0, acc[2][0], 0, 0, 0);
        acc[2][1] = __builtin_amdgcn_mfma_f32_16x16x32_f16(m2, B1, acc[2][1], 0, 0, 0);
        acc[2][2] = __builtin_amdgcn_mfma_f32_16x16x32_f16(m2, B2, acc[2][2], 0, 0, 0);
        acc[2][3] = __builtin_amdgcn_mfma_f32_16x16x32_f16(m2, B3, acc[2][3], 0, 0, 0);
        acc[3][0] = __builtin_amdgcn_mfma_f32_16x16x32_f16(m3, B0, acc[3][0], 0, 0, 0);
        acc[3][1] = __builtin_amdgcn_mfma_f32_16x16x32_f16(m3, B1, acc[3][1], 0, 0, 0);
        acc[3][2] = __builtin_amdgcn_mfma_f32_16x16x32_f16(m3, B2, acc[3][2], 0, 0, 0);
        acc[3][3] = __builtin_amdgcn_mfma_f32_16x16x32_f16(m3, B3, acc[3][3], 0, 0, 0);
        if (c <= 15)
            __asm__ volatile("s_waitcnt vmcnt(2)\ns_barrier" ::: "memory");
        else if (c == 16)
            __asm__ volatile("s_waitcnt vmcnt(0)\ns_barrier" ::: "memory");
        else
            __asm__ volatile("s_barrier" ::: "memory");
    }
}

// Merged step: logical z<8 -> L0 at time t, z>=8 -> L1 at time t-1.
__global__ __launch_bounds__(512, 4) void step_merged(
    int l0_active, int l1_active, int last0, int last1,
    const float* __restrict__ x, const ushort* __restrict__ Wx0F,
    const ushort* __restrict__ Wh0S, const float* __restrict__ b0,
    const ushort* __restrict__ h0_prev, float* __restrict__ c0,
    ushort* __restrict__ h0_out, float* __restrict__ oh0, float* __restrict__ oc0,
    const ushort* __restrict__ xin, const ushort* __restrict__ Wx1S,
    const ushort* __restrict__ Wh1S, const float* __restrict__ b1,
    const ushort* __restrict__ h1_prev, float* __restrict__ c1,
    ushort* __restrict__ h1_out, float* __restrict__ oh1, float* __restrict__ oc1)
{
    __shared__ __align__(16) ushort tile[NCELL * TSTRIDE];   // 25,920 B
    __shared__ __align__(16) ushort bbuf[3 * 8192];          // 49,152 B ring
    ushort* xa = bbuf;                                       // alias: slot 0

    // Bijective XCD swizzle: P = z*32+y*4+x (x-fastest dispatch order);
    // logical z=(P&7)+8*(P>>8), y=(P>>5)&7, x=(P>>3)&3.
    const int P  = (blockIdx.z * gridDim.y + blockIdx.y) * gridDim.x + blockIdx.x;
    const int xb = (P >> 3) & 3;
    const int yb = (P >> 5) & 7;
    const int zb = (P & 7) + ((P >> 8) << 3);

    bool isL1; int b;
    if (l0_active && l1_active) { isL1 = (zb >= 8); b = zb & 7; }
    else                        { isL1 = (l1_active != 0); b = zb; }

    const int tid = threadIdx.x;
    const int lane = tid & 63;
    const int w = tid >> 6;             // wave id 0..7
    const int fq = w & 3;               // f quad (N split)
    const int mw = w >> 2;              // 4-row band (M split), 0..1
    const int colA = lane & 15;
    const int quad = (lane >> 4) & 3;
    const int x0 = xb * 16, y0 = yb * 8;
    const int blk = yb * 4 + xb;        // 0..31 px-tile id
    const int f = fq * 16 + colA;

    const ushort* h_prev = isL1 ? h1_prev : h0_prev;
    const float*  bias   = isL1 ? b1 : b0;
    float*        cbuf   = isL1 ? c1 : c0;
    ushort*       hout   = isL1 ? h1_out : h0_out;
    float* hf = isL1 ? (last1 ? oh1 : nullptr) : (last0 ? oh0 : nullptr);
    float* cf = isL1 ? (last1 ? oc1 : nullptr) : (last0 ? oc0 : nullptr);

    // ---- pre-issue first conv's frames 0,1 (slots 1,2; no LDS conflict) ----
    if (!isL1) {
        if (h_prev) preissue(Wh0S, bbuf, tid);
    } else {
        preissue(Wx1S, bbuf, tid);
    }

    // ---- stage first A source (overlaps with the DMA above) ----
    if (!isL1) {
        const float* xs = x + (size_t)b * 40960;
        for (int idx = tid; idx < 4096; idx += 512) {
            int e = idx & 7, li = (idx >> 3) & 63, r = idx >> 9;   // r 0..7
            int ci = li & 15, qi = li >> 4;
            int k = qi * 8 + e;
            ushort val = 0;
            if (k < 9) {
                int dy = (k * 86) >> 8;
                int dx = k - dy * 3;
                int y = y0 + r + dy - 1, xx = x0 + ci + dx - 1;
                if ((unsigned)y < 64u && (unsigned)xx < 64u)
                    val = f2h(xs[(y << 6) + xx]);
            }
            xa[idx] = val;
        }
        if (h_prev) stage(h_prev + (size_t)b * 4096 * 64, tile, y0, x0, tid);
    } else {
        stage(xin + (size_t)b * 4096 * 64, tile, y0, x0, tid);
    }
    __syncthreads();   // drains vmcnt(0): tile + xa + preissued frames ready

    // ---- init accumulators with bias ----
    f32x4 acc[4][4];
#pragma unroll
    for (int g = 0; g < 4; ++g) {
        float bv = bias[g * 64 + f];
#pragma unroll
        for (int mt = 0; mt < 4; ++mt) {
            acc[mt][g][0] = bv; acc[mt][g][1] = bv;
            acc[mt][g][2] = bv; acc[mt][g][3] = bv;
        }
    }

    if (!isL1) {
        // x-conv via MFMA (K=32-padded Wx0 frames); xa lives in slot 0
        f16x8 xb4[4];
#pragma unroll
        for (int g = 0; g < 4; ++g)
            xb4[g] = *(const f16x8*)&Wx0F[((fq * 4 + g) * 64 + lane) * 8];
#pragma unroll
        for (int mt = 0; mt < 4; ++mt) {
            f16x8 xaf = *(const f16x8*)&xa[(mw * 4 + mt) * 512 + lane * 8];
#pragma unroll
            for (int g = 0; g < 4; ++g)
                acc[mt][g] = __builtin_amdgcn_mfma_f32_16x16x32_f16(
                    xaf, xb4[g], acc[mt][g], 0, 0, 0);
        }
        __syncthreads();   // xa reads done before conv overwrites slot 0
        if (h_prev) conv_stream(tile, Wh0S, bbuf, acc, fq, mw, lane, tid);
    } else {
        conv_stream(tile, Wx1S, bbuf, acc, fq, mw, lane, tid);
        if (h_prev) {
            preissue(Wh1S, bbuf, tid);    // overlaps with h-restage below
            stage(h_prev + (size_t)b * 4096 * 64, tile, y0, x0, tid);
            __syncthreads();              // drains vmcnt(0) + tile visible
            conv_stream(tile, Wh1S, bbuf, acc, fq, mw, lane, tid);
        }
    }

    // ---- LSTM pointwise epilogue ----
    // cbuf private layout (lane-linear): ((((b*32+blk)*8+w)*4+mt)*4+reg)*64+lane
#pragma unroll
    for (int mt = 0; mt < 4; ++mt) {
        const int y = y0 + mw * 4 + mt;
#pragma unroll
        for (int reg = 0; reg < 4; ++reg) {
            const int xx = x0 + quad * 4 + reg;
            const size_t cidx = (((((size_t)b * 32 + blk) * 8 + w) * 4 + mt) * 4
                                 + reg) * 64 + lane;
            const size_t pidx = ((size_t)b * 4096 + (y << 6) + xx) * 64 + f;
            float cp = h_prev ? cbuf[cidx] : 0.f;
            float iv = hsig(acc[mt][0][reg]);
            float fv = hsig(acc[mt][1][reg]);
            float gv = ftanh(acc[mt][2][reg]);
            float ov = hsig(acc[mt][3][reg]);
            float cn = fmaf(fv, cp, iv * gv);
            float hn = ov * ftanh(cn);
            cbuf[cidx] = cn;
            hout[pidx] = f2h(hn);
            if (hf) { hf[pidx] = hn; cf[pidx] = cn; }
        }
    }
}

extern "C" void kernel_launch(void* const* d_in, const int* in_sizes, int n_in,
                              void* d_out, int out_size, void* d_ws, size_t ws_size,
                              hipStream_t stream) {
    const float* x   = (const float*)d_in[0];
    const float* Wx0 = (const float*)d_in[1];
    const float* Wh0 = (const float*)d_in[2];
    const float* b0  = (const float*)d_in[3];
    const float* Wx1 = (const float*)d_in[4];
    const float* Wh1 = (const float*)d_in[5];
    const float* b1  = (const float*)d_in[6];
    float* out = (float*)d_out;
    char* ws = (char*)d_ws;

    ushort* h0buf[2] = { (ushort*)ws, (ushort*)(ws + 4u * 1024 * 1024) };
    ushort* h1buf[2] = { (ushort*)(ws + 8u * 1024 * 1024), (ushort*)(ws + 12u * 1024 * 1024) };
    float* c0 = (float*)(ws + 16u * 1024 * 1024);
    float* c1 = (float*)(ws + 24u * 1024 * 1024);
    ushort* Wh0S = (ushort*)(ws + 32u * 1024 * 1024);
    ushort* Wx1S = Wh0S + 147456;
    ushort* Wh1S = Wx1S + 147456;
    ushort* Wx0F = Wh1S + 147456;

    prep_w<<<dim3(576, 4), 256, 0, stream>>>(Wh0, Wx1, Wh1, Wx0,
                                             Wh0S, Wx1S, Wh1S, Wx0F);

    for (int t = 0; t <= 10; ++t) {
        const int has0 = (t < 10), has1 = (t >= 1);
        const int s = t - 1;
        const int tx = has0 ? t : 9;
        dim3 grid(4, 8, (has0 && has1) ? 16 : 8);
        step_merged<<<grid, 512, 0, stream>>>(
            has0, has1, (t == 9), (s == 9),
            x + (size_t)tx * 4096, Wx0F,
            (t >= 1) ? Wh0S : nullptr, b0,
            (t >= 1 && has0) ? h0buf[(t - 1) & 1] : nullptr, c0,
            h0buf[t & 1], out, out + BHWF,
            has1 ? h0buf[s & 1] : nullptr, Wx1S,
            Wh1S, b1,
            (s >= 1) ? h1buf[(s - 1) & 1] : nullptr, c1,
            h1buf[s & 1], out + 2 * (size_t)BHWF, out + 3 * (size_t)BHWF);
    }
}

// Round 9
// 403.782 us; speedup vs baseline: 1.0173x; 1.0004x over previous
//
#include <hip/hip_runtime.h>

// ConvLSTM2D x2 encoder — fp16 MFMA implicit-GEMM, round 17.
// A/B ledger: R14=383 (base), R15=+swizzle+setprio=410.8, R16=+swizzle+
// preissue=404 -> swizzle ~ +20us (XCD=P%8 assumption unverified; natural
// x-fastest order already pairs 1 L0 + 1 L1 per CU), setprio ~ +7 (m190
// lockstep null), preissue ~ 0..-2 (sound; absmax stable). This round:
// REVERT swizzle, KEEP preissue (frames 0,1 fly under the tile/xa stage;
// ring slot=(c+1)%3 so slot0/xa only overwritten after conv entry).
// Residual model: heavy ~35us vs LDS floor ~17 + MFMA 3.5 -> barrier
// convergence tax; all catalog levers for it measured null/negative here.

typedef _Float16 f16x8 __attribute__((ext_vector_type(8)));
typedef float f32x4 __attribute__((ext_vector_type(4)));

#define BHWF (8 * 64 * 64 * 64)
#define TSTRIDE 72                // LDS cell stride (fp16 units)
#define NCELL 180                 // 10 rows x 18 cols halo tile (16x8 px)

__device__ __forceinline__ float hsig(float x) {
    return fminf(fmaxf(fmaf(0.2f, x, 0.5f), 0.0f), 1.0f);
}

__device__ __forceinline__ float ftanh(float x) {
    float e = __expf(2.0f * x);
    return fmaf(-2.0f, __builtin_amdgcn_rcpf(e + 1.0f), 1.0f);
}

__device__ __forceinline__ ushort f2h(float f) {
    _Float16 h = (_Float16)f;     // v_cvt_f16_f32, RNE
    return __builtin_bit_cast(ushort, h);
}

// y=0..2: swizzle fp32 W[k=576][n=256] -> fp16 fragment-linear frames
//   (frame = tap*2+kc, 8192 ushorts each). y=3: Wx0 K=32-padded frames.
__global__ void prep_w(const float* __restrict__ s0, const float* __restrict__ s1,
                       const float* __restrict__ s2, const float* __restrict__ wx0,
                       ushort* __restrict__ d0, ushort* __restrict__ d1,
                       ushort* __restrict__ d2, ushort* __restrict__ dx0) {
    int o = blockIdx.x * 256 + threadIdx.x;
    if (blockIdx.y == 3) {
        if (o < 8192) {
            int e    = o & 7;
            int lane = (o >> 3) & 63;
            int g    = (o >> 9) & 3;
            int fq   = (o >> 11) & 3;
            int k = (lane >> 4) * 8 + e;
            int n = g * 64 + fq * 16 + (lane & 15);
            dx0[o] = (k < 9) ? f2h(wx0[k * 256 + n]) : (ushort)0;
        }
        return;
    }
    const float* s[3] = { s0, s1, s2 };
    ushort* d[3] = { d0, d1, d2 };
    int e    = o & 7;
    int lane = (o >> 3) & 63;
    int g    = (o >> 9) & 3;
    int fq   = (o >> 11) & 3;
    int kc   = (o >> 13) & 1;
    int tap  = o >> 14;
    int n = g * 64 + fq * 16 + (lane & 15);
    int k = tap * 64 + kc * 32 + (lane >> 4) * 8 + e;
    d[blockIdx.y][o] = f2h(s[blockIdx.y][k * 256 + n]);
}

// Stage 10x18 halo tile of fp16 [4096][64] image into LDS [cell][TSTRIDE].
__device__ __forceinline__ void stage(const ushort* __restrict__ src,
                                      ushort* __restrict__ tile,
                                      int y0, int x0, int tid) {
    for (int v = tid; v < NCELL * 8; v += 512) {
        int cell = v >> 3, j = v & 7;
        int r = cell / 18, cc = cell - r * 18;
        int y = y0 - 1 + r, xx = x0 - 1 + cc;
        uint4 dv = make_uint4(0u, 0u, 0u, 0u);
        if ((unsigned)y < 64u && (unsigned)xx < 64u)
            dv = ((const uint4*)src)[(size_t)((y << 6) + xx) * 8 + j];
        *(uint4*)&tile[cell * TSTRIDE + j * 8] = dv;
    }
}

__device__ __forceinline__ int frame_of(int c) {
    int kc = c / 9, r = c % 9, dxx = r / 3, dyy = r % 3;
    return (dyy * 3 + dxx) * 2 + kc;
}

// One frame = 16KB staged block-wide by 512 threads: 2 DMA ops x 16B/thread.
__device__ __forceinline__ void dma_frame(const ushort* __restrict__ src,
                                          ushort* __restrict__ dst, int tid) {
    __builtin_amdgcn_global_load_lds(
        (const __attribute__((address_space(1))) unsigned int*)(src + tid * 8),
        (__attribute__((address_space(3))) unsigned int*)(dst + tid * 8),
        16, 0, 0);
    __builtin_amdgcn_global_load_lds(
        (const __attribute__((address_space(1))) unsigned int*)(src + 4096 + tid * 8),
        (__attribute__((address_space(3))) unsigned int*)(dst + 4096 + tid * 8),
        16, 0, 0);
}

// Pre-issue frames 0,1 into ring slots 1,2 (slot = (c+1)%3). Safe anywhere
// after the previous conv's final barrier; overlaps with stage global-loads.
__device__ __forceinline__ void preissue(const ushort* __restrict__ WS,
                                         ushort* __restrict__ bbuf, int tid) {
    dma_frame(WS + (size_t)frame_of(0) * 8192, bbuf + 8192, tid);
    dma_frame(WS + (size_t)frame_of(1) * 8192, bbuf + 16384, tid);
}

// 3x3x64 conv, block tile 16x8 px, 8 waves (mw 2-way M, fq 4-way N).
// Caller must preissue() frames 0,1 and __syncthreads() (which drains
// vmcnt(0)) before calling. Frame c lives in slot (c+1)%3; chunk c issues
// f(c+2) into slot c%3 (fenced by chunk c-1's barrier). Counted vmcnt(2),
// raw s_barrier. A-rows mw*4+{1..4} cached C1..C4 per (kc,dx) group.
__device__ __forceinline__ void conv_stream(const ushort* __restrict__ tile,
                                            const ushort* __restrict__ WS,
                                            ushort* __restrict__ bbuf,
                                            f32x4 (&acc)[4][4],
                                            int fq, int mw, int lane, int tid) {
    const int colA = lane & 15;
    const int quad = (lane >> 4) & 3;
    f16x8 C1, C2, C3, C4;
#pragma unroll
    for (int c = 0; c < 18; ++c) {
        if (c <= 15)
            dma_frame(WS + (size_t)frame_of(c + 2) * 8192,
                      bbuf + (c % 3) * 8192, tid);
        const int kc = c / 9, dx = (c % 9) / 3, dy = c % 3;
        const ushort* arow = &tile[((mw * 4) * 18 + colA + dx) * TSTRIDE
                                   + kc * 32 + quad * 8];
        f16x8 m0, m1, m2, m3;
        if (dy == 0) {
            m0 = *(const f16x8*)&arow[0 * 18 * TSTRIDE];
            C1 = *(const f16x8*)&arow[1 * 18 * TSTRIDE];
            C2 = *(const f16x8*)&arow[2 * 18 * TSTRIDE];
            C3 = *(const f16x8*)&arow[3 * 18 * TSTRIDE];
            m1 = C1; m2 = C2; m3 = C3;
        } else if (dy == 1) {
            C4 = *(const f16x8*)&arow[4 * 18 * TSTRIDE];
            m0 = C1; m1 = C2; m2 = C3; m3 = C4;
        } else {
            f16x8 a5 = *(const f16x8*)&arow[5 * 18 * TSTRIDE];
            m0 = C2; m1 = C3; m2 = C4; m3 = a5;
        }
        const ushort* bp = bbuf + ((c + 1) % 3) * 8192 + fq * 2048 + lane * 8;
        f16x8 B0 = *(const f16x8*)&bp[0];
        f16x8 B1 = *(const f16x8*)&bp[512];
        f16x8 B2 = *(const f16x8*)&bp[1024];
        f16x8 B3 = *(const f16x8*)&bp[1536];
        acc[0][0] = __builtin_amdgcn_mfma_f32_16x16x32_f16(m0, B0, acc[0][0], 0, 0, 0);
        acc[0][1] = __builtin_amdgcn_mfma_f32_16x16x32_f16(m0, B1, acc[0][1], 0, 0, 0);
        acc[0][2] = __builtin_amdgcn_mfma_f32_16x16x32_f16(m0, B2, acc[0][2], 0, 0, 0);
        acc[0][3] = __builtin_amdgcn_mfma_f32_16x16x32_f16(m0, B3, acc[0][3], 0, 0, 0);
        acc[1][0] = __builtin_amdgcn_mfma_f32_16x16x32_f16(m1, B0, acc[1][0], 0, 0, 0);
        acc[1][1] = __builtin_amdgcn_mfma_f32_16x16x32_f16(m1, B1, acc[1][1], 0, 0, 0);
        acc[1][2] = __builtin_amdgcn_mfma_f32_16x16x32_f16(m1, B2, acc[1][2], 0, 0, 0);
        acc[1][3] = __builtin_amdgcn_mfma_f32_16x16x32_f16(m1, B3, acc[1][3], 0, 0, 0);
        acc[2][0] = __builtin_amdgcn_mfma_f32_16x16x32_f16(m2, B0, acc[2][0], 0, 0, 0);
        acc[2][1] = __builtin_amdgcn_mfma_f32_16x16x32_f16(m2, B1, acc[2][1], 0, 0, 0);
        acc[2][2] = __builtin_amdgcn_mfma_f32_16x16x32_f16(m2, B2, acc[2][2], 0, 0, 0);
        acc[2][3] = __builtin_amdgcn_mfma_f32_16x16x32_f16(m2, B3, acc[2][3], 0, 0, 0);
        acc[3][0] = __builtin_amdgcn_mfma_f32_16x16x32_f16(m3, B0, acc[3][0], 0, 0, 0);
        acc[3][1] = __builtin_amdgcn_mfma_f32_16x16x32_f16(m3, B1, acc[3][1], 0, 0, 0);
        acc[3][2] = __builtin_amdgcn_mfma_f32_16x16x32_f16(m3, B2, acc[3][2], 0, 0, 0);
        acc[3][3] = __builtin_amdgcn_mfma_f32_16x16x32_f16(m3, B3, acc[3][3], 0, 0, 0);
        if (c <= 15)
            __asm__ volatile("s_waitcnt vmcnt(2)\ns_barrier" ::: "memory");
        else if (c == 16)
            __asm__ volatile("s_waitcnt vmcnt(0)\ns_barrier" ::: "memory");
        else
            __asm__ volatile("s_barrier" ::: "memory");
    }
}

// Merged step: z<8 -> L0 at time t, z>=8 -> L1 at time t-1 (independent work).
__global__ __launch_bounds__(512, 4) void step_merged(
    int l0_active, int l1_active, int last0, int last1,
    const float* __restrict__ x, const ushort* __restrict__ Wx0F,
    const ushort* __restrict__ Wh0S, const float* __restrict__ b0,
    const ushort* __restrict__ h0_prev, float* __restrict__ c0,
    ushort* __restrict__ h0_out, float* __restrict__ oh0, float* __restrict__ oc0,
    const ushort* __restrict__ xin, const ushort* __restrict__ Wx1S,
    const ushort* __restrict__ Wh1S, const float* __restrict__ b1,
    const ushort* __restrict__ h1_prev, float* __restrict__ c1,
    ushort* __restrict__ h1_out, float* __restrict__ oh1, float* __restrict__ oc1)
{
    __shared__ __align__(16) ushort tile[NCELL * TSTRIDE];   // 25,920 B
    __shared__ __align__(16) ushort bbuf[3 * 8192];          // 49,152 B ring
    ushort* xa = bbuf;                                       // alias: slot 0

    const int z = blockIdx.z;
    bool isL1; int b;
    if (l0_active && l1_active) { isL1 = (z >= 8); b = z & 7; }
    else                        { isL1 = (l1_active != 0); b = z; }

    const int tid = threadIdx.x;
    const int lane = tid & 63;
    const int w = tid >> 6;             // wave id 0..7
    const int fq = w & 3;               // f quad (N split)
    const int mw = w >> 2;              // 4-row band (M split), 0..1
    const int colA = lane & 15;
    const int quad = (lane >> 4) & 3;
    const int x0 = blockIdx.x * 16, y0 = blockIdx.y * 8;
    const int blk = blockIdx.y * 4 + blockIdx.x;   // 0..31 px-tile id
    const int f = fq * 16 + colA;

    const ushort* h_prev = isL1 ? h1_prev : h0_prev;
    const float*  bias   = isL1 ? b1 : b0;
    float*        cbuf   = isL1 ? c1 : c0;
    ushort*       hout   = isL1 ? h1_out : h0_out;
    float* hf = isL1 ? (last1 ? oh1 : nullptr) : (last0 ? oh0 : nullptr);
    float* cf = isL1 ? (last1 ? oc1 : nullptr) : (last0 ? oc0 : nullptr);

    // ---- pre-issue first conv's frames 0,1 (slots 1,2; no LDS conflict) ----
    if (!isL1) {
        if (h_prev) preissue(Wh0S, bbuf, tid);
    } else {
        preissue(Wx1S, bbuf, tid);
    }

    // ---- stage first A source (overlaps with the DMA above) ----
    if (!isL1) {
        const float* xs = x + (size_t)b * 40960;
        for (int idx = tid; idx < 4096; idx += 512) {
            int e = idx & 7, li = (idx >> 3) & 63, r = idx >> 9;   // r 0..7
            int ci = li & 15, qi = li >> 4;
            int k = qi * 8 + e;
            ushort val = 0;
            if (k < 9) {
                int dy = (k * 86) >> 8;
                int dx = k - dy * 3;
                int y = y0 + r + dy - 1, xx = x0 + ci + dx - 1;
                if ((unsigned)y < 64u && (unsigned)xx < 64u)
                    val = f2h(xs[(y << 6) + xx]);
            }
            xa[idx] = val;
        }
        if (h_prev) stage(h_prev + (size_t)b * 4096 * 64, tile, y0, x0, tid);
    } else {
        stage(xin + (size_t)b * 4096 * 64, tile, y0, x0, tid);
    }
    __syncthreads();   // drains vmcnt(0): tile + xa + preissued frames ready

    // ---- init accumulators with bias ----
    f32x4 acc[4][4];
#pragma unroll
    for (int g = 0; g < 4; ++g) {
        float bv = bias[g * 64 + f];
#pragma unroll
        for (int mt = 0; mt < 4; ++mt) {
            acc[mt][g][0] = bv; acc[mt][g][1] = bv;
            acc[mt][g][2] = bv; acc[mt][g][3] = bv;
        }
    }

    if (!isL1) {
        // x-conv via MFMA (K=32-padded Wx0 frames); xa lives in slot 0
        f16x8 xb4[4];
#pragma unroll
        for (int g = 0; g < 4; ++g)
            xb4[g] = *(const f16x8*)&Wx0F[((fq * 4 + g) * 64 + lane) * 8];
#pragma unroll
        for (int mt = 0; mt < 4; ++mt) {
            f16x8 xaf = *(const f16x8*)&xa[(mw * 4 + mt) * 512 + lane * 8];
#pragma unroll
            for (int g = 0; g < 4; ++g)
                acc[mt][g] = __builtin_amdgcn_mfma_f32_16x16x32_f16(
                    xaf, xb4[g], acc[mt][g], 0, 0, 0);
        }
        __syncthreads();   // xa reads done before conv overwrites slot 0
        if (h_prev) conv_stream(tile, Wh0S, bbuf, acc, fq, mw, lane, tid);
    } else {
        conv_stream(tile, Wx1S, bbuf, acc, fq, mw, lane, tid);
        if (h_prev) {
            preissue(Wh1S, bbuf, tid);    // overlaps with h-restage below
            stage(h_prev + (size_t)b * 4096 * 64, tile, y0, x0, tid);
            __syncthreads();              // drains vmcnt(0) + tile visible
            conv_stream(tile, Wh1S, bbuf, acc, fq, mw, lane, tid);
        }
    }

    // ---- LSTM pointwise epilogue ----
    // cbuf private layout (lane-linear): ((((b*32+blk)*8+w)*4+mt)*4+reg)*64+lane
#pragma unroll
    for (int mt = 0; mt < 4; ++mt) {
        const int y = y0 + mw * 4 + mt;
#pragma unroll
        for (int reg = 0; reg < 4; ++reg) {
            const int xx = x0 + quad * 4 + reg;
            const size_t cidx = (((((size_t)b * 32 + blk) * 8 + w) * 4 + mt) * 4
                                 + reg) * 64 + lane;
            const size_t pidx = ((size_t)b * 4096 + (y << 6) + xx) * 64 + f;
            float cp = h_prev ? cbuf[cidx] : 0.f;
            float iv = hsig(acc[mt][0][reg]);
            float fv = hsig(acc[mt][1][reg]);
            float gv = ftanh(acc[mt][2][reg]);
            float ov = hsig(acc[mt][3][reg]);
            float cn = fmaf(fv, cp, iv * gv);
            float hn = ov * ftanh(cn);
            cbuf[cidx] = cn;
            hout[pidx] = f2h(hn);
            if (hf) { hf[pidx] = hn; cf[pidx] = cn; }
        }
    }
}

extern "C" void kernel_launch(void* const* d_in, const int* in_sizes, int n_in,
                              void* d_out, int out_size, void* d_ws, size_t ws_size,
                              hipStream_t stream) {
    const float* x   = (const float*)d_in[0];
    const float* Wx0 = (const float*)d_in[1];
    const float* Wh0 = (const float*)d_in[2];
    const float* b0  = (const float*)d_in[3];
    const float* Wx1 = (const float*)d_in[4];
    const float* Wh1 = (const float*)d_in[5];
    const float* b1  = (const float*)d_in[6];
    float* out = (float*)d_out;
    char* ws = (char*)d_ws;

    ushort* h0buf[2] = { (ushort*)ws, (ushort*)(ws + 4u * 1024 * 1024) };
    ushort* h1buf[2] = { (ushort*)(ws + 8u * 1024 * 1024), (ushort*)(ws + 12u * 1024 * 1024) };
    float* c0 = (float*)(ws + 16u * 1024 * 1024);
    float* c1 = (float*)(ws + 24u * 1024 * 1024);
    ushort* Wh0S = (ushort*)(ws + 32u * 1024 * 1024);
    ushort* Wx1S = Wh0S + 147456;
    ushort* Wh1S = Wx1S + 147456;
    ushort* Wx0F = Wh1S + 147456;

    prep_w<<<dim3(576, 4), 256, 0, stream>>>(Wh0, Wx1, Wh1, Wx0,
                                             Wh0S, Wx1S, Wh1S, Wx0F);

    for (int t = 0; t <= 10; ++t) {
        const int has0 = (t < 10), has1 = (t >= 1);
        const int s = t - 1;
        const int tx = has0 ? t : 9;
        dim3 grid(4, 8, (has0 && has1) ? 16 : 8);
        step_merged<<<grid, 512, 0, stream>>>(
            has0, has1, (t == 9), (s == 9),
            x + (size_t)tx * 4096, Wx0F,
            (t >= 1) ? Wh0S : nullptr, b0,
            (t >= 1 && has0) ? h0buf[(t - 1) & 1] : nullptr, c0,
            h0buf[t & 1], out, out + BHWF,
            has1 ? h0buf[s & 1] : nullptr, Wx1S,
            Wh1S, b1,
            (s >= 1) ? h1buf[(s - 1) & 1] : nullptr, c1,
            h1buf[s & 1], out + 2 * (size_t)BHWF, out + 3 * (size_t)BHWF);
    }
}

// Round 10
// 400.220 us; speedup vs baseline: 1.0263x; 1.0089x over previous
//
#include <hip/hip_runtime.h>

// ConvLSTM2D x2 encoder — fp16 MFMA implicit-GEMM, round 18.
// R16/R17 post-mortem: preissue was the +21us regression. Mechanism: vmcnt
// retires IN ORDER (m135) — issuing 4 big weight-DMA ops before the stage
// loop's tight load->use chains makes every compiler vmcnt wait for a stage
// load drain the older 32KB weight fetch first; stage serializes behind it
// at all 3 conv entries. Lesson: never issue bulk prefetch ahead of
// latency-sensitive scalar loads. This round: EXACT R14 revert (383us,
// absmax 0.0156 bit-exact): conv_stream re-owns entry sync + f0/f1 issue +
// vmcnt(2) first-wait; ring read slot c%3, write (c+2)%3; A-cache C1..C4.
// Ledger (all measured): setprio -, swizzle 0, preissue -, M=128 spill,
// 1 blk/CU imbalance, B->VGPR L2-trap. Next lever if 383 reproduces:
// persistent cooperative kernel (512 blocks = exact 2/CU capacity).

typedef _Float16 f16x8 __attribute__((ext_vector_type(8)));
typedef float f32x4 __attribute__((ext_vector_type(4)));

#define BHWF (8 * 64 * 64 * 64)
#define TSTRIDE 72                // LDS cell stride (fp16 units)
#define NCELL 180                 // 10 rows x 18 cols halo tile (16x8 px)

__device__ __forceinline__ float hsig(float x) {
    return fminf(fmaxf(fmaf(0.2f, x, 0.5f), 0.0f), 1.0f);
}

__device__ __forceinline__ float ftanh(float x) {
    float e = __expf(2.0f * x);
    return fmaf(-2.0f, __builtin_amdgcn_rcpf(e + 1.0f), 1.0f);
}

__device__ __forceinline__ ushort f2h(float f) {
    _Float16 h = (_Float16)f;     // v_cvt_f16_f32, RNE
    return __builtin_bit_cast(ushort, h);
}

// y=0..2: swizzle fp32 W[k=576][n=256] -> fp16 fragment-linear frames
//   (frame = tap*2+kc, 8192 ushorts each). y=3: Wx0 K=32-padded frames.
__global__ void prep_w(const float* __restrict__ s0, const float* __restrict__ s1,
                       const float* __restrict__ s2, const float* __restrict__ wx0,
                       ushort* __restrict__ d0, ushort* __restrict__ d1,
                       ushort* __restrict__ d2, ushort* __restrict__ dx0) {
    int o = blockIdx.x * 256 + threadIdx.x;
    if (blockIdx.y == 3) {
        if (o < 8192) {
            int e    = o & 7;
            int lane = (o >> 3) & 63;
            int g    = (o >> 9) & 3;
            int fq   = (o >> 11) & 3;
            int k = (lane >> 4) * 8 + e;
            int n = g * 64 + fq * 16 + (lane & 15);
            dx0[o] = (k < 9) ? f2h(wx0[k * 256 + n]) : (ushort)0;
        }
        return;
    }
    const float* s[3] = { s0, s1, s2 };
    ushort* d[3] = { d0, d1, d2 };
    int e    = o & 7;
    int lane = (o >> 3) & 63;
    int g    = (o >> 9) & 3;
    int fq   = (o >> 11) & 3;
    int kc   = (o >> 13) & 1;
    int tap  = o >> 14;
    int n = g * 64 + fq * 16 + (lane & 15);
    int k = tap * 64 + kc * 32 + (lane >> 4) * 8 + e;
    d[blockIdx.y][o] = f2h(s[blockIdx.y][k * 256 + n]);
}

// Stage 10x18 halo tile of fp16 [4096][64] image into LDS [cell][TSTRIDE].
__device__ __forceinline__ void stage(const ushort* __restrict__ src,
                                      ushort* __restrict__ tile,
                                      int y0, int x0, int tid) {
    for (int v = tid; v < NCELL * 8; v += 512) {
        int cell = v >> 3, j = v & 7;
        int r = cell / 18, cc = cell - r * 18;
        int y = y0 - 1 + r, xx = x0 - 1 + cc;
        uint4 dv = make_uint4(0u, 0u, 0u, 0u);
        if ((unsigned)y < 64u && (unsigned)xx < 64u)
            dv = ((const uint4*)src)[(size_t)((y << 6) + xx) * 8 + j];
        *(uint4*)&tile[cell * TSTRIDE + j * 8] = dv;
    }
}

__device__ __forceinline__ int frame_of(int c) {
    int kc = c / 9, r = c % 9, dxx = r / 3, dyy = r % 3;
    return (dyy * 3 + dxx) * 2 + kc;
}

// One frame = 16KB staged block-wide by 512 threads: 2 DMA ops x 16B/thread.
__device__ __forceinline__ void dma_frame(const ushort* __restrict__ src,
                                          ushort* __restrict__ dst, int tid) {
    __builtin_amdgcn_global_load_lds(
        (const __attribute__((address_space(1))) unsigned int*)(src + tid * 8),
        (__attribute__((address_space(3))) unsigned int*)(dst + tid * 8),
        16, 0, 0);
    __builtin_amdgcn_global_load_lds(
        (const __attribute__((address_space(1))) unsigned int*)(src + 4096 + tid * 8),
        (__attribute__((address_space(3))) unsigned int*)(dst + 4096 + tid * 8),
        16, 0, 0);
}

// 3x3x64 conv, block tile 16x8 px, 8 waves (mw 2-way M, fq 4-way N).
// B: LDS 3-deep ring, 1 frame/chunk staged cooperatively (2 DMA ops),
// counted vmcnt(2), raw s_barrier. Chunk c: kc=c/9, dx=(c%9)/3, dy=c%3.
// A: rows mw*4+{1..4} cached in C1..C4 per (kc,dx) group; rows 0/5 read
// fresh at dy==0/2 (all refs static; c-loop fully unrolled).
__device__ __forceinline__ void conv_stream(const ushort* __restrict__ tile,
                                            const ushort* __restrict__ WS,
                                            ushort* __restrict__ bbuf,
                                            f32x4 (&acc)[4][4],
                                            int fq, int mw, int lane, int tid) {
    const int colA = lane & 15;
    const int quad = (lane >> 4) & 3;
    __syncthreads();                       // prior readers of bbuf/xa done
    dma_frame(WS + (size_t)frame_of(0) * 8192, bbuf, tid);
    dma_frame(WS + (size_t)frame_of(1) * 8192, bbuf + 8192, tid);
    __asm__ volatile("s_waitcnt vmcnt(2)\ns_barrier" ::: "memory");
    f16x8 C1, C2, C3, C4;
#pragma unroll
    for (int c = 0; c < 18; ++c) {
        if (c <= 15)
            dma_frame(WS + (size_t)frame_of(c + 2) * 8192,
                      bbuf + ((c + 2) % 3) * 8192, tid);
        const int kc = c / 9, dx = (c % 9) / 3, dy = c % 3;
        const ushort* arow = &tile[((mw * 4) * 18 + colA + dx) * TSTRIDE
                                   + kc * 32 + quad * 8];
        f16x8 m0, m1, m2, m3;
        if (dy == 0) {
            m0 = *(const f16x8*)&arow[0 * 18 * TSTRIDE];
            C1 = *(const f16x8*)&arow[1 * 18 * TSTRIDE];
            C2 = *(const f16x8*)&arow[2 * 18 * TSTRIDE];
            C3 = *(const f16x8*)&arow[3 * 18 * TSTRIDE];
            m1 = C1; m2 = C2; m3 = C3;
        } else if (dy == 1) {
            C4 = *(const f16x8*)&arow[4 * 18 * TSTRIDE];
            m0 = C1; m1 = C2; m2 = C3; m3 = C4;
        } else {
            f16x8 a5 = *(const f16x8*)&arow[5 * 18 * TSTRIDE];
            m0 = C2; m1 = C3; m2 = C4; m3 = a5;
        }
        const ushort* bp = bbuf + (c % 3) * 8192 + fq * 2048 + lane * 8;
        f16x8 B0 = *(const f16x8*)&bp[0];
        f16x8 B1 = *(const f16x8*)&bp[512];
        f16x8 B2 = *(const f16x8*)&bp[1024];
        f16x8 B3 = *(const f16x8*)&bp[1536];
        acc[0][0] = __builtin_amdgcn_mfma_f32_16x16x32_f16(m0, B0, acc[0][0], 0, 0, 0);
        acc[0][1] = __builtin_amdgcn_mfma_f32_16x16x32_f16(m0, B1, acc[0][1], 0, 0, 0);
        acc[0][2] = __builtin_amdgcn_mfma_f32_16x16x32_f16(m0, B2, acc[0][2], 0, 0, 0);
        acc[0][3] = __builtin_amdgcn_mfma_f32_16x16x32_f16(m0, B3, acc[0][3], 0, 0, 0);
        acc[1][0] = __builtin_amdgcn_mfma_f32_16x16x32_f16(m1, B0, acc[1][0], 0, 0, 0);
        acc[1][1] = __builtin_amdgcn_mfma_f32_16x16x32_f16(m1, B1, acc[1][1], 0, 0, 0);
        acc[1][2] = __builtin_amdgcn_mfma_f32_16x16x32_f16(m1, B2, acc[1][2], 0, 0, 0);
        acc[1][3] = __builtin_amdgcn_mfma_f32_16x16x32_f16(m1, B3, acc[1][3], 0, 0, 0);
        acc[2][0] = __builtin_amdgcn_mfma_f32_16x16x32_f16(m2, B0, acc[2][0], 0, 0, 0);
        acc[2][1] = __builtin_amdgcn_mfma_f32_16x16x32_f16(m2, B1, acc[2][1], 0, 0, 0);
        acc[2][2] = __builtin_amdgcn_mfma_f32_16x16x32_f16(m2, B2, acc[2][2], 0, 0, 0);
        acc[2][3] = __builtin_amdgcn_mfma_f32_16x16x32_f16(m2, B3, acc[2][3], 0, 0, 0);
        acc[3][0] = __builtin_amdgcn_mfma_f32_16x16x32_f16(m3, B0, acc[3][0], 0, 0, 0);
        acc[3][1] = __builtin_amdgcn_mfma_f32_16x16x32_f16(m3, B1, acc[3][1], 0, 0, 0);
        acc[3][2] = __builtin_amdgcn_mfma_f32_16x16x32_f16(m3, B2, acc[3][2], 0, 0, 0);
        acc[3][3] = __builtin_amdgcn_mfma_f32_16x16x32_f16(m3, B3, acc[3][3], 0, 0, 0);
        if (c <= 15)
            __asm__ volatile("s_waitcnt vmcnt(2)\ns_barrier" ::: "memory");
        else if (c == 16)
            __asm__ volatile("s_waitcnt vmcnt(0)\ns_barrier" ::: "memory");
        else
            __asm__ volatile("s_barrier" ::: "memory");
    }
}

// Merged step: z<8 -> L0 at time t, z>=8 -> L1 at time t-1 (independent work).
__global__ __launch_bounds__(512, 4) void step_merged(
    int l0_active, int l1_active, int last0, int last1,
    const float* __restrict__ x, const ushort* __restrict__ Wx0F,
    const ushort* __restrict__ Wh0S, const float* __restrict__ b0,
    const ushort* __restrict__ h0_prev, float* __restrict__ c0,
    ushort* __restrict__ h0_out, float* __restrict__ oh0, float* __restrict__ oc0,
    const ushort* __restrict__ xin, const ushort* __restrict__ Wx1S,
    const ushort* __restrict__ Wh1S, const float* __restrict__ b1,
    const ushort* __restrict__ h1_prev, float* __restrict__ c1,
    ushort* __restrict__ h1_out, float* __restrict__ oh1, float* __restrict__ oc1)
{
    __shared__ __align__(16) ushort tile[NCELL * TSTRIDE];   // 25,920 B
    __shared__ __align__(16) ushort bbuf[3 * 8192];          // 49,152 B ring
    ushort* xa = bbuf;                                       // alias: slot 0

    const int z = blockIdx.z;
    bool isL1; int b;
    if (l0_active && l1_active) { isL1 = (z >= 8); b = z & 7; }
    else                        { isL1 = (l1_active != 0); b = z; }

    const int tid = threadIdx.x;
    const int lane = tid & 63;
    const int w = tid >> 6;             // wave id 0..7
    const int fq = w & 3;               // f quad (N split)
    const int mw = w >> 2;              // 4-row band (M split), 0..1
    const int colA = lane & 15;
    const int quad = (lane >> 4) & 3;
    const int x0 = blockIdx.x * 16, y0 = blockIdx.y * 8;
    const int blk = blockIdx.y * 4 + blockIdx.x;   // 0..31 px-tile id
    const int f = fq * 16 + colA;

    const ushort* h_prev = isL1 ? h1_prev : h0_prev;
    const float*  bias   = isL1 ? b1 : b0;
    float*        cbuf   = isL1 ? c1 : c0;
    ushort*       hout   = isL1 ? h1_out : h0_out;
    float* hf = isL1 ? (last1 ? oh1 : nullptr) : (last0 ? oh0 : nullptr);
    float* cf = isL1 ? (last1 ? oc1 : nullptr) : (last0 ? oc0 : nullptr);

    // ---- stage first A source ----
    if (!isL1) {
        const float* xs = x + (size_t)b * 40960;
        for (int idx = tid; idx < 4096; idx += 512) {
            int e = idx & 7, li = (idx >> 3) & 63, r = idx >> 9;   // r 0..7
            int ci = li & 15, qi = li >> 4;
            int k = qi * 8 + e;
            ushort val = 0;
            if (k < 9) {
                int dy = (k * 86) >> 8;
                int dx = k - dy * 3;
                int y = y0 + r + dy - 1, xx = x0 + ci + dx - 1;
                if ((unsigned)y < 64u && (unsigned)xx < 64u)
                    val = f2h(xs[(y << 6) + xx]);
            }
            xa[idx] = val;
        }
        if (h_prev) stage(h_prev + (size_t)b * 4096 * 64, tile, y0, x0, tid);
    } else {
        stage(xin + (size_t)b * 4096 * 64, tile, y0, x0, tid);
    }
    __syncthreads();

    // ---- init accumulators with bias ----
    f32x4 acc[4][4];
#pragma unroll
    for (int g = 0; g < 4; ++g) {
        float bv = bias[g * 64 + f];
#pragma unroll
        for (int mt = 0; mt < 4; ++mt) {
            acc[mt][g][0] = bv; acc[mt][g][1] = bv;
            acc[mt][g][2] = bv; acc[mt][g][3] = bv;
        }
    }

    if (!isL1) {
        // x-conv via MFMA (K=32-padded Wx0 frames); xa lives in slot 0
        f16x8 xb4[4];
#pragma unroll
        for (int g = 0; g < 4; ++g)
            xb4[g] = *(const f16x8*)&Wx0F[((fq * 4 + g) * 64 + lane) * 8];
#pragma unroll
        for (int mt = 0; mt < 4; ++mt) {
            f16x8 xaf = *(const f16x8*)&xa[(mw * 4 + mt) * 512 + lane * 8];
#pragma unroll
            for (int g = 0; g < 4; ++g)
                acc[mt][g] = __builtin_amdgcn_mfma_f32_16x16x32_f16(
                    xaf, xb4[g], acc[mt][g], 0, 0, 0);
        }
        if (h_prev) conv_stream(tile, Wh0S, bbuf, acc, fq, mw, lane, tid);
    } else {
        conv_stream(tile, Wx1S, bbuf, acc, fq, mw, lane, tid);
        if (h_prev) {
            __syncthreads();
            stage(h_prev + (size_t)b * 4096 * 64, tile, y0, x0, tid);
            __syncthreads();
            conv_stream(tile, Wh1S, bbuf, acc, fq, mw, lane, tid);
        }
    }

    // ---- LSTM pointwise epilogue ----
    // cbuf private layout (lane-linear): ((((b*32+blk)*8+w)*4+mt)*4+reg)*64+lane
#pragma unroll
    for (int mt = 0; mt < 4; ++mt) {
        const int y = y0 + mw * 4 + mt;
#pragma unroll
        for (int reg = 0; reg < 4; ++reg) {
            const int xx = x0 + quad * 4 + reg;
            const size_t cidx = (((((size_t)b * 32 + blk) * 8 + w) * 4 + mt) * 4
                                 + reg) * 64 + lane;
            const size_t pidx = ((size_t)b * 4096 + (y << 6) + xx) * 64 + f;
            float cp = h_prev ? cbuf[cidx] : 0.f;
            float iv = hsig(acc[mt][0][reg]);
            float fv = hsig(acc[mt][1][reg]);
            float gv = ftanh(acc[mt][2][reg]);
            float ov = hsig(acc[mt][3][reg]);
            float cn = fmaf(fv, cp, iv * gv);
            float hn = ov * ftanh(cn);
            cbuf[cidx] = cn;
            hout[pidx] = f2h(hn);
            if (hf) { hf[pidx] = hn; cf[pidx] = cn; }
        }
    }
}

extern "C" void kernel_launch(void* const* d_in, const int* in_sizes, int n_in,
                              void* d_out, int out_size, void* d_ws, size_t ws_size,
                              hipStream_t stream) {
    const float* x   = (const float*)d_in[0];
    const float* Wx0 = (const float*)d_in[1];
    const float* Wh0 = (const float*)d_in[2];
    const float* b0  = (const float*)d_in[3];
    const float* Wx1 = (const float*)d_in[4];
    const float* Wh1 = (const float*)d_in[5];
    const float* b1  = (const float*)d_in[6];
    float* out = (float*)d_out;
    char* ws = (char*)d_ws;

    ushort* h0buf[2] = { (ushort*)ws, (ushort*)(ws + 4u * 1024 * 1024) };
    ushort* h1buf[2] = { (ushort*)(ws + 8u * 1024 * 1024), (ushort*)(ws + 12u * 1024 * 1024) };
    float* c0 = (float*)(ws + 16u * 1024 * 1024);
    float* c1 = (float*)(ws + 24u * 1024 * 1024);
    ushort* Wh0S = (ushort*)(ws + 32u * 1024 * 1024);
    ushort* Wx1S = Wh0S + 147456;
    ushort* Wh1S = Wx1S + 147456;
    ushort* Wx0F = Wh1S + 147456;

    prep_w<<<dim3(576, 4), 256, 0, stream>>>(Wh0, Wx1, Wh1, Wx0,
                                             Wh0S, Wx1S, Wh1S, Wx0F);

    for (int t = 0; t <= 10; ++t) {
        const int has0 = (t < 10), has1 = (t >= 1);
        const int s = t - 1;
        const int tx = has0 ? t : 9;
        dim3 grid(4, 8, (has0 && has1) ? 16 : 8);
        step_merged<<<grid, 512, 0, stream>>>(
            has0, has1, (t == 9), (s == 9),
            x + (size_t)tx * 4096, Wx0F,
            (t >= 1) ? Wh0S : nullptr, b0,
            (t >= 1 && has0) ? h0buf[(t - 1) & 1] : nullptr, c0,
            h0buf[t & 1], out, out + BHWF,
            has1 ? h0buf[s & 1] : nullptr, Wx1S,
            Wh1S, b1,
            (s >= 1) ? h1buf[(s - 1) & 1] : nullptr, c1,
            h1buf[s & 1], out + 2 * (size_t)BHWF, out + 3 * (size_t)BHWF);
    }
}